// Round 13
// baseline (164.321 us; speedup 1.0000x reference)
//
#include <hip/hip_runtime.h>

// ============================================================================
// ROUND 13 — BLOCK-COOPERATIVE LDS SLAB. A block's 8 waves are 8
// consecutive x-sorted queries (slabs ~99% shared). Stage the union slab
// ONCE per block into LDS (coalesced), scan from LDS (~120cy, no L2
// contention) instead of 8x redundant L2 traffic (FETCH 16.3MB -> ~5MB).
// LDS lifetime-shared: union buffer (29.7KB incl 2KB over-read slack)
// overlays {scr 10KB + sW2t 17KB}; W2 restaged after the scan barrier.
// Total ~50KB -> still 3 blocks/CU. Block-uniform global-scan fallback if
// union count > 3456 (13-sigma, ~never). prep/head verbatim r12 (banked
// 160.9).
// ============================================================================

#define N 8192
#define C 64
#define S 16

static constexpr float BN_INV = 0.9999950000374997f; // 1/sqrt(1+1e-5)
static constexpr float LN_EPS = 1e-5f;

typedef _Float16 f16x8 __attribute__((ext_vector_type(8)));
typedef _Float16 f16x4 __attribute__((ext_vector_type(4)));
typedef float f32x4 __attribute__((ext_vector_type(4)));

__device__ __forceinline__ void sort2(unsigned& x, unsigned& y)
{
    unsigned lo = min(x, y);
    unsigned hi = max(x, y);
    x = lo;
    y = hi;
}

__device__ __forceinline__ unsigned med3u(unsigned a, unsigned b, unsigned c)
{
    unsigned r;
    asm("v_med3_u32 %0, %1, %2, %3" : "=v"(r) : "v"(a), "v"(b), "v"(c));
    return r;
}

__device__ __forceinline__ void insert4(unsigned& a0, unsigned& a1,
                                        unsigned& a2, unsigned& a3,
                                        unsigned k)
{
    unsigned m = min(a3, k);
    unsigned n1 = med3u(a0, a1, m);
    unsigned n2 = med3u(a1, a2, m);
    a3 = max(a2, m);
    a0 = min(a0, m);
    a1 = n1;
    a2 = n2;
}

__device__ __forceinline__ int mbcnt64(unsigned long long m)
{
    int lo = __builtin_amdgcn_mbcnt_lo((unsigned)m, 0);
    return __builtin_amdgcn_mbcnt_hi((unsigned)(m >> 32), lo);
}

// d2 from packed coords (x|y<<8|z<<16, byte3 = 0).
__device__ __forceinline__ unsigned d2_packed(unsigned pk, unsigned qq,
                                              unsigned qpk2, int qx, int qy,
                                              int qz)
{
#if __has_builtin(__builtin_amdgcn_udot4)
    return __builtin_amdgcn_udot4(pk, pk, qq, false) -
           __builtin_amdgcn_udot4(pk, qpk2, 0u, false);
#else
    int x = (int)(pk & 255u), y = (int)((pk >> 8) & 255u),
        z = (int)((pk >> 16) & 255u);
    int dx = x - qx, dy = y - qy, dz = z - qz;
    (void)qpk2;
    return (unsigned)(dx * dx + dy * dy + dz * dz);
#endif
}

// ---------------------------------------------------------------------------
// K0: PREP (verbatim r12) — blocks 0..63: qkv GEMM; block 64: counting sort
// by x; blocks 65..69: coalesced-read weight transposes.
// ---------------------------------------------------------------------------
__global__ __launch_bounds__(512) void prep_kernel(
    const int4* __restrict__ idx4, const float* __restrict__ feats,
    const float* __restrict__ Wq, const float* __restrict__ bq,
    const float* __restrict__ Wk, const float* __restrict__ bk,
    const float* __restrict__ Wv, const float* __restrict__ bv,
    float* __restrict__ xq, float* __restrict__ xk, float* __restrict__ xv,
    const float* __restrict__ Ww1, const float* __restrict__ Ww2,
    const float* __restrict__ Wc1, const float* __restrict__ Wc2,
    const float* __restrict__ Wc3,
    _Float16* __restrict__ W1tG, _Float16* __restrict__ W2tG,
    _Float16* __restrict__ Wc1tG, _Float16* __restrict__ Wc2tG,
    _Float16* __restrict__ Wc3tG,
    uint2* __restrict__ sorted, int* __restrict__ cdf)
{
    extern __shared__ char smem[];
    const int t = threadIdx.x;
    const int lane = t & 63;
    const int wv = t >> 6;
    const int bx = blockIdx.x;
    if (bx == 64) {
        // ---------------- counting sort by x ----------------
        __shared__ int whist[8][128];
        __shared__ int wrun[8][128];
        __shared__ int tot[128];
        __shared__ int binbase[128];
        for (int i = t; i < 1024; i += 512) ((int*)whist)[i] = 0;
        __syncthreads();
        int4 c[16];
#pragma unroll
        for (int i = 0; i < 16; i++) c[i] = idx4[i * 512 + t];
#pragma unroll
        for (int i = 0; i < 16; i++) atomicAdd(&whist[wv][c[i].y], 1);
        __syncthreads();
        if (t < 128) {
            int acc = 0;
#pragma unroll
            for (int w = 0; w < 8; w++) {
                wrun[w][t] = acc;
                acc += whist[w][t];
            }
            tot[t] = acc;
        }
        __syncthreads();
        if (t < 64) {
            int h0 = tot[2 * t], h1 = tot[2 * t + 1];
            int s = h0 + h1;
            int incl = s;
#pragma unroll
            for (int d = 1; d < 64; d <<= 1) {
                int nb = __shfl_up(incl, d, 64);
                if (t >= d) incl += nb;
            }
            int excl = incl - s;
            binbase[2 * t] = excl;
            binbase[2 * t + 1] = excl + h0;
            cdf[2 * t] = excl;
            cdf[2 * t + 1] = excl + h0;
            if (t == 63) cdf[128] = 8192;
        }
        __syncthreads();
        if (t < 128) {
            int bb = binbase[t];
#pragma unroll
            for (int w = 0; w < 8; w++) wrun[w][t] += bb;
        }
        __syncthreads();
#pragma unroll
        for (int i = 0; i < 16; i++) {
            int4 cc = c[i];
            unsigned pk = (unsigned)cc.y | ((unsigned)cc.z << 8) |
                          ((unsigned)cc.w << 16);
            int pos = atomicAdd(&wrun[wv][cc.y], 1);
            sorted[pos] = make_uint2(pk, (unsigned)(i * 512 + t));
        }
    } else if (bx < 64) {
        // ---------------- qkv GEMM (verbatim) ----------------
        _Float16* sBt = (_Float16*)smem;
        float* sbias = (float*)(smem + 192 * 72 * 2);
        const int col = lane & 15, g = lane >> 4;
        const int row0w = bx * 128 + wv * 16;
        {
            const float* Ws[3] = {Wq, Wk, Wv};
#pragma unroll
            for (int m = 0; m < 3; m++) {
                int k = t >> 3, nb = (t & 7) * 8;
                const float4* src = (const float4*)(Ws[m] + k * 64 + nb);
                float4 w0 = src[0], w1 = src[1];
                _Float16* dst = &sBt[(m * 64 + nb) * 72 + k];
                dst[0 * 72] = (_Float16)w0.x; dst[1 * 72] = (_Float16)w0.y;
                dst[2 * 72] = (_Float16)w0.z; dst[3 * 72] = (_Float16)w0.w;
                dst[4 * 72] = (_Float16)w1.x; dst[5 * 72] = (_Float16)w1.y;
                dst[6 * 72] = (_Float16)w1.z; dst[7 * 72] = (_Float16)w1.w;
            }
            if (t < 64) sbias[t] = bq[t];
            else if (t < 128) sbias[t] = bk[t - 64];
            else if (t < 192) sbias[t] = bv[t - 128];
        }
        __syncthreads();
        f16x8 au[2];
#pragma unroll
        for (int kc = 0; kc < 2; kc++) {
            const float4* src = (const float4*)
                (feats + (row0w + col) * 64 + kc * 32 + g * 8);
            float4 v0 = src[0], v1 = src[1];
            au[kc][0] = (_Float16)v0.x; au[kc][1] = (_Float16)v0.y;
            au[kc][2] = (_Float16)v0.z; au[kc][3] = (_Float16)v0.w;
            au[kc][4] = (_Float16)v1.x; au[kc][5] = (_Float16)v1.y;
            au[kc][6] = (_Float16)v1.z; au[kc][7] = (_Float16)v1.w;
        }
        float* outs[3] = {xq, xk, xv};
#pragma unroll
        for (int f = 0; f < 12; f++) {
            f32x4 acc;
            float bias = sbias[f * 16 + col];
#pragma unroll
            for (int r = 0; r < 4; r++) acc[r] = bias;
#pragma unroll
            for (int kc = 0; kc < 2; kc++) {
                f16x8 bw = *(const f16x8*)
                    &sBt[(f * 16 + col) * 72 + kc * 32 + g * 8];
                acc = __builtin_amdgcn_mfma_f32_16x16x32_f16(au[kc], bw, acc,
                                                             0, 0, 0);
            }
            float* o = outs[f >> 2];
            int cg = (f & 3) * 16 + col;
#pragma unroll
            for (int r = 0; r < 4; r++)
                o[(row0w + g * 4 + r) * 64 + cg] = acc[r];
        }
    } else if (bx == 65) {
        for (int i4 = t; i4 < 2048; i4 += 512) {
            const float4 v = ((const float4*)Ww1)[i4];
            const int j = i4 * 4, k = j >> 7, n = j & 127;
            W1tG[(n + 0) * 64 + k] = (_Float16)v.x;
            W1tG[(n + 1) * 64 + k] = (_Float16)v.y;
            W1tG[(n + 2) * 64 + k] = (_Float16)v.z;
            W1tG[(n + 3) * 64 + k] = (_Float16)v.w;
        }
    } else if (bx == 66) {
        for (int i4 = t; i4 < 2048; i4 += 512) {
            const float4 v = ((const float4*)Ww2)[i4];
            const int j = i4 * 4, k = j >> 6, n = j & 63;
            W2tG[(n + 0) * 128 + k] = (_Float16)v.x;
            W2tG[(n + 1) * 128 + k] = (_Float16)v.y;
            W2tG[(n + 2) * 128 + k] = (_Float16)v.z;
            W2tG[(n + 3) * 128 + k] = (_Float16)v.w;
        }
    } else if (bx == 67) {
        for (int i4 = t; i4 < 4096; i4 += 512) {
            const float4 v = ((const float4*)Wc1)[i4];
            const int j = i4 * 4, k = j >> 7, n = j & 127;
            Wc1tG[(n + 0) * 128 + k] = (_Float16)v.x;
            Wc1tG[(n + 1) * 128 + k] = (_Float16)v.y;
            Wc1tG[(n + 2) * 128 + k] = (_Float16)v.z;
            Wc1tG[(n + 3) * 128 + k] = (_Float16)v.w;
        }
    } else if (bx == 68) {
        for (int i4 = t; i4 < 4096; i4 += 512) {
            const float4 v = ((const float4*)Wc2)[i4];
            const int j = i4 * 4, k = j >> 7, n = j & 127;
            Wc2tG[(n + 0) * 128 + k] = (_Float16)v.x;
            Wc2tG[(n + 1) * 128 + k] = (_Float16)v.y;
            Wc2tG[(n + 2) * 128 + k] = (_Float16)v.z;
            Wc2tG[(n + 3) * 128 + k] = (_Float16)v.w;
        }
    } else {
        for (int i4 = t; i4 < 2048; i4 += 512) {
            const float4 v = ((const float4*)Wc3)[i4];
            const int j = i4 * 4, k = j >> 6, n = j & 63;
            Wc3tG[(n + 0) * 128 + k] = (_Float16)v.x;
            Wc3tG[(n + 1) * 128 + k] = (_Float16)v.y;
            Wc3tG[(n + 2) * 128 + k] = (_Float16)v.z;
            Wc3tG[(n + 3) * 128 + k] = (_Float16)v.w;
        }
    }
}

// ---------------------------------------------------------------------------
// K1: MERGED knn+attn with block-cooperative LDS slab.
// LDS layout: sW1t (18KB, whole kernel) | uSh union 29.7KB:
//   scan phase:  slab = (uint2*)uSh, capacity 3456 entries + 256 slack
//   attn phase:  scr(wave) = uSh[wv*640], sW2t = uSh[5120..13824)
// 3 barriers: (1) slab+W1 staged; (2) slab reads done -> scr/W2 writes ok;
// (3) W2 restaged -> GEMM2. Block-uniform global-scan fallback if
// ucount > 3456. De-spilled body + (512,6) kept from r11/r12.
// ---------------------------------------------------------------------------
__global__ __launch_bounds__(512, 6) void knnattn_kernel(
    const int4* __restrict__ idx4, const uint2* __restrict__ sorted,
    const int* __restrict__ cdf,
    const float* __restrict__ xq, const float* __restrict__ xk,
    const float* __restrict__ xv,
    const float* __restrict__ Wp1, const float* __restrict__ pg,
    const float* __restrict__ pb, const float* __restrict__ Wp2,
    const float* __restrict__ bp2,
    const float* __restrict__ wg1, const float* __restrict__ wb1,
    const _Float16* __restrict__ W1tG,
    const float* __restrict__ wg2, const float* __restrict__ wb2,
    const _Float16* __restrict__ W2tG,
    float* __restrict__ attn)
{
    __shared__ _Float16 sW1t[128 * 72];    // 18.0 KB
    __shared__ _Float16 uSh[14848];        // 29.0 KB union (slab | scr+W2t)
    __shared__ int sKnn[8][16];            // 0.5 KB per-wave knn handoff
    __shared__ float sWp1[48], sPg[16], sPb[16];
    __shared__ float sg2[128], sb2[128];

    const int t = threadIdx.x;
    const int lane = t & 63;
    const int wv = t >> 6;
    const int col = lane & 15, g = lane >> 4;

    // ---- W1 + consts staging ----
    for (int i = t; i < 1024; i += 512) {
        int n = i >> 3, ko = i & 7;
        *(f16x8*)&sW1t[n * 72 + ko * 8] =
            *(const f16x8*)&W1tG[n * 64 + ko * 8];
    }
    if (t < 48) sWp1[t] = Wp1[t];
    if (t < 16) { sPg[t] = pg[t] * BN_INV; sPb[t] = pb[t]; }
    if (t >= 64 && t < 192) {
        int o = t - 64;
        sg2[o] = wg2[o] * BN_INV;
        sb2[o] = wb2[o];
    }
    float g1c[4], b1c[4], bp2c[4];
#pragma unroll
    for (int f = 0; f < 4; f++) {
        int c = f * 16 + col;
        g1c[f] = wg1[c] * BN_INV; b1c[f] = wb1[c];
        bp2c[f] = bp2[c];
    }

    // ---- query identity + earliest possible xq gather ----
    const int pos = blockIdx.x * 8 + wv;
    const uint2 sq = sorted[pos];
    const int q = (int)sq.y;
    const int qx = (int)(sq.x & 255u);
    const int qy = (int)((sq.x >> 8) & 255u);
    const int qz = (int)(sq.x >> 16);
    float xqv[4];
#pragma unroll
    for (int f = 0; f < 4; f++) xqv[f] = xq[q * 64 + f * 16 + col];

    // ---- union slab bounds (block-uniform: queries are x-sorted) ----
    const uint2 sqa = sorted[blockIdx.x * 8];
    const uint2 sqb = sorted[blockIdx.x * 8 + 7];
    const int bxa = (int)(sqa.x & 255u);
    const int bxb = (int)(sqb.x & 255u);
    const int ulo = (bxa > 18) ? bxa - 18 : 0;
    const int uhi = (bxb < 109) ? bxb + 18 : 127;
    const int ustart = cdf[ulo];
    const int uend = cdf[uhi + 1];
    const int ubase = ustart & ~1;
    const int ucount = uend - ubase;
    const bool fits = (ucount <= 3456);
    uint2* slab = (uint2*)uSh;
    if (fits) {
        for (int i = t; i * 2 < ucount; i += 512)
            *(uint4*)&slab[i * 2] = *(const uint4*)(sorted + ubase + i * 2);
    }
    __syncthreads();  // barrier 1: slab + sW1t + consts staged

    // ---- phase 1: per-wave KNN ----
    {
        const unsigned qq = (unsigned)(qx * qx + qy * qy + qz * qz);
#if __has_builtin(__builtin_amdgcn_udot4)
        const unsigned qpk2 = (unsigned)(2 * qx) |
                              ((unsigned)(2 * qy) << 8) |
                              ((unsigned)(2 * qz) << 16);
#else
        const unsigned qpk2 = 0;
#endif
        const int lo = (qx > 18) ? qx - 18 : 0;
        const int hi = (qx < 109) ? qx + 18 : 127;
        const int start = cdf[lo];
        const int end = cdf[hi + 1];
        const int nc = end - start;
        const int s0 = start & ~1;                // 16B-align reads
        const int iters = (end - s0 + 255) >> 8;  // 256 cands/wave/iter

        unsigned a0 = 0xFFFFFFFFu, a1 = 0xFFFFFFFFu, a2 = 0xFFFFFFFFu,
                 a3 = 0xFFFFFFFFu;
        unsigned b0 = 0xFFFFFFFFu, b1 = 0xFFFFFFFFu, b2 = 0xFFFFFFFFu,
                 b3 = 0xFFFFFFFFu;
        if (fits) {
            // LDS scan (slab over-read covered by 256-entry slack)
            for (int ii = 0; ii < iters; ++ii) {
                const int j0 = s0 + ii * 256 + lane * 2;
                const int j1 = j0 + 128;
                const uint4 cd0 = *(const uint4*)&slab[j0 - ubase];
                const uint4 cd1 = *(const uint4*)&slab[j1 - ubase];
                unsigned d00 = d2_packed(cd0.x, qq, qpk2, qx, qy, qz);
                unsigned d01 = d2_packed(cd0.z, qq, qpk2, qx, qy, qz);
                unsigned d10 = d2_packed(cd1.x, qq, qpk2, qx, qy, qz);
                unsigned d11 = d2_packed(cd1.z, qq, qpk2, qx, qy, qz);
                unsigned k00 = (j0 >= start && j0 < end)
                    ? (d00 << 13) + cd0.y : 0xFFFFFFFFu;
                unsigned k01 = (j0 + 1 < end) ? (d01 << 13) + cd0.w
                                              : 0xFFFFFFFFu;
                unsigned k10 = (j1 < end) ? (d10 << 13) + cd1.y
                                          : 0xFFFFFFFFu;
                unsigned k11 = (j1 + 1 < end) ? (d11 << 13) + cd1.w
                                              : 0xFFFFFFFFu;
                insert4(a0, a1, a2, a3, k00);
                insert4(a0, a1, a2, a3, k10);
                insert4(b0, b1, b2, b3, k01);
                insert4(b0, b1, b2, b3, k11);
            }
        } else {
            // global scan (r12 path, depth-2 prefetch)
            uint4 cd0 = *(const uint4*)(sorted + s0 + lane * 2);
            uint4 cd1 = *(const uint4*)(sorted + s0 + lane * 2 + 128);
            for (int ii = 0; ii < iters; ++ii) {
                const int j0 = s0 + ii * 256 + lane * 2;
                const int j1 = j0 + 128;
                const uint4 nx0 = *(const uint4*)(sorted + j0 + 256);
                const uint4 nx1 = *(const uint4*)(sorted + j0 + 384);
                unsigned d00 = d2_packed(cd0.x, qq, qpk2, qx, qy, qz);
                unsigned d01 = d2_packed(cd0.z, qq, qpk2, qx, qy, qz);
                unsigned d10 = d2_packed(cd1.x, qq, qpk2, qx, qy, qz);
                unsigned d11 = d2_packed(cd1.z, qq, qpk2, qx, qy, qz);
                unsigned k00 = (j0 >= start && j0 < end)
                    ? (d00 << 13) + cd0.y : 0xFFFFFFFFu;
                unsigned k01 = (j0 + 1 < end) ? (d01 << 13) + cd0.w
                                              : 0xFFFFFFFFu;
                unsigned k10 = (j1 < end) ? (d10 << 13) + cd1.y
                                          : 0xFFFFFFFFu;
                unsigned k11 = (j1 + 1 < end) ? (d11 << 13) + cd1.w
                                              : 0xFFFFFFFFu;
                insert4(a0, a1, a2, a3, k00);
                insert4(a0, a1, a2, a3, k10);
                insert4(b0, b1, b2, b3, k01);
                insert4(b0, b1, b2, b3, k11);
                cd0 = nx0;
                cd1 = nx1;
            }
        }
        const unsigned LIM = 1u << 22;
        int c_all = __popcll(__ballot(a0 < LIM)) +
                    __popcll(__ballot(a1 < LIM)) +
                    __popcll(__ballot(a2 < LIM)) +
                    __popcll(__ballot(a3 < LIM)) +
                    __popcll(__ballot(b0 < LIM)) +
                    __popcll(__ballot(b1 < LIM)) +
                    __popcll(__ballot(b2 < LIM)) +
                    __popcll(__ballot(b3 < LIM));
        const bool deep = (c_all >= 16);
        unsigned prefix = 0u;
#pragma unroll
        for (int bit = 21; bit >= 0; --bit) {
            unsigned cand = prefix | (1u << bit);
            int c = __popcll(__ballot(a0 < cand)) +
                    __popcll(__ballot(a1 < cand)) +
                    __popcll(__ballot(a2 < cand)) +
                    __popcll(__ballot(a3 < cand)) +
                    __popcll(__ballot(b0 < cand)) +
                    __popcll(__ballot(b1 < cand)) +
                    __popcll(__ballot(b2 < cand)) +
                    __popcll(__ballot(b3 < cand));
            if (c < 16) prefix = cand;
        }
        const unsigned T = prefix;
        {
            unsigned long long m0 = __ballot(a0 <= T);
            unsigned long long m1 = __ballot(a1 <= T);
            unsigned long long m2 = __ballot(a2 <= T);
            unsigned long long m3 = __ballot(a3 <= T);
            unsigned long long m4 = __ballot(b0 <= T);
            unsigned long long m5 = __ballot(b1 <= T);
            unsigned long long m6 = __ballot(b2 <= T);
            unsigned long long m7 = __ballot(b3 <= T);
            int p1 = __popcll(m0);
            int p2 = p1 + __popcll(m1);
            int p3 = p2 + __popcll(m2);
            int p4 = p3 + __popcll(m3);
            int p5 = p4 + __popcll(m4);
            int p6 = p5 + __popcll(m5);
            int p7 = p6 + __popcll(m6);
            int* dst = sKnn[wv];
            if (a0 <= T) dst[mbcnt64(m0)] = (int)(a0 & 8191u);
            if (a1 <= T) dst[p1 + mbcnt64(m1)] = (int)(a1 & 8191u);
            if (a2 <= T) dst[p2 + mbcnt64(m2)] = (int)(a2 & 8191u);
            if (a3 <= T) dst[p3 + mbcnt64(m3)] = (int)(a3 & 8191u);
            if (b0 <= T) dst[p4 + mbcnt64(m4)] = (int)(b0 & 8191u);
            if (b1 <= T) dst[p5 + mbcnt64(m5)] = (int)(b1 & 8191u);
            if (b2 <= T) dst[p6 + mbcnt64(m6)] = (int)(b2 & 8191u);
            if (b3 <= T) dst[p7 + mbcnt64(m7)] = (int)(b3 & 8191u);
        }
        const unsigned d2T = T >> 13;
        unsigned long long badm = __ballot(a3 < T) | __ballot(b3 < T);
        if (!deep || badm != 0ull || d2T > 324u || nc < 16) {
            // Exact rescan from GLOBAL (rare).
            int R2 = deep ? min(127, (int)sqrtf((float)d2T) + 1) : 127;
            if (nc < 16) R2 = 127;
            const int lo2 = (qx > R2) ? qx - R2 : 0;
            const int hi2 = (qx + R2 < 127) ? qx + R2 : 127;
            const int sF = cdf[lo2];
            const int eF = cdf[hi2 + 1];
            const int sA = sF & ~3;                   // 16B alignment
            const int itF = (eF - sA + 255) >> 8;     // 4 cands/lane/iter
            unsigned c0 = 0xFFFFFFFFu, c1 = 0xFFFFFFFFu, c2 = 0xFFFFFFFFu,
                     c3 = 0xFFFFFFFFu, c4 = 0xFFFFFFFFu, c5 = 0xFFFFFFFFu,
                     c6 = 0xFFFFFFFFu, c7 = 0xFFFFFFFFu, c8 = 0xFFFFFFFFu,
                     c9 = 0xFFFFFFFFu, c10 = 0xFFFFFFFFu, c11 = 0xFFFFFFFFu,
                     c12 = 0xFFFFFFFFu, c13 = 0xFFFFFFFFu, c14 = 0xFFFFFFFFu,
                     c15 = 0xFFFFFFFFu;
            for (int ii = 0; ii < itF; ++ii) {
                const int jb = sA + ii * 256 + lane * 4;
                const uint4 w0 = *(const uint4*)(sorted + jb);
                const uint4 w1 = *(const uint4*)(sorted + jb + 2);
                unsigned kk[4];
                kk[0] = (jb >= sF && jb < eF)
                    ? (d2_packed(w0.x, qq, qpk2, qx, qy, qz) << 13) + w0.y
                    : 0xFFFFFFFFu;
                kk[1] = (jb + 1 >= sF && jb + 1 < eF)
                    ? (d2_packed(w0.z, qq, qpk2, qx, qy, qz) << 13) + w0.w
                    : 0xFFFFFFFFu;
                kk[2] = (jb + 2 >= sF && jb + 2 < eF)
                    ? (d2_packed(w1.x, qq, qpk2, qx, qy, qz) << 13) + w1.y
                    : 0xFFFFFFFFu;
                kk[3] = (jb + 3 >= sF && jb + 3 < eF)
                    ? (d2_packed(w1.z, qq, qpk2, qx, qy, qz) << 13) + w1.w
                    : 0xFFFFFFFFu;
#pragma unroll
                for (int u = 0; u < 4; ++u) {
                    c15 = min(c15, kk[u]);
                    sort2(c14, c15); sort2(c13, c14); sort2(c12, c13);
                    sort2(c11, c12); sort2(c10, c11); sort2(c9, c10);
                    sort2(c8, c9);   sort2(c7, c8);   sort2(c6, c7);
                    sort2(c5, c6);   sort2(c4, c5);   sort2(c3, c4);
                    sort2(c2, c3);   sort2(c1, c2);   sort2(c0, c1);
                }
            }
            for (int r = 0; r < 16; ++r) {
                unsigned m = c0;
                m = min(m, (unsigned)__shfl_xor((int)m, 1, 64));
                m = min(m, (unsigned)__shfl_xor((int)m, 2, 64));
                m = min(m, (unsigned)__shfl_xor((int)m, 4, 64));
                m = min(m, (unsigned)__shfl_xor((int)m, 8, 64));
                m = min(m, (unsigned)__shfl_xor((int)m, 16, 64));
                m = min(m, (unsigned)__shfl_xor((int)m, 32, 64));
                if (lane == r) sKnn[wv][r] = (int)(m & 8191u);
                bool win = (c0 == m);
                c0 = win ? c1 : c0;    c1 = win ? c2 : c1;
                c2 = win ? c3 : c2;    c3 = win ? c4 : c3;
                c4 = win ? c5 : c4;    c5 = win ? c6 : c5;
                c6 = win ? c7 : c6;    c7 = win ? c8 : c7;
                c8 = win ? c9 : c8;    c9 = win ? c10 : c9;
                c10 = win ? c11 : c10; c11 = win ? c12 : c11;
                c12 = win ? c13 : c12; c13 = win ? c14 : c13;
                c14 = win ? c15 : c14; c15 = win ? 0xFFFFFFFFu : c15;
            }
        }
    }

    // ---- pre-barrier gathers (sKnn wave-local; latency hides under
    //      barrier 2). xvv stays deferred past GEMM2. ----
    const int jA = sKnn[wv][col];
    const int4 jC = *(const int4*)&sKnn[wv][g * 4];
    const int jr[4] = {jC.x, jC.y, jC.z, jC.w};
    const int4 pc = idx4[jA];
    float xkv[4][4];
#pragma unroll
    for (int r = 0; r < 4; r++)
#pragma unroll
        for (int f = 0; f < 4; f++)
            xkv[r][f] = xk[jr[r] * 64 + f * 16 + col];

    __syncthreads();  // barrier 2: all slab reads done -> union reusable

    // ---- restage W2 into union (consumed at GEMM2, past barrier 3) ----
    _Float16* sW2t = &uSh[5120];
    for (int i = t; i < 1024; i += 512) {
        int m = i >> 4, ko = i & 15;
        *(f16x8*)&sW2t[m * 136 + ko * 8] =
            *(const f16x8*)&W2tG[m * 128 + ko * 8];
    }
    _Float16* scr = &uSh[wv * 640];

    // ---- p_r (pr stays LIVE to the einsum) ----
    const float px = (float)(pc.y - qx);
    const float py = (float)(pc.z - qy);
    const float pz = (float)(pc.w - qz);
    f32x4 pr[4];
#if __has_builtin(__builtin_amdgcn_mfma_f32_16x16x16f16)
    {
        f16x4 aph;
#pragma unroll
        for (int j = 0; j < 4; j++) {
            int h = g * 4 + j;
            float v = px * sWp1[h] + py * sWp1[16 + h] + pz * sWp1[32 + h];
            v = fmaxf(v * sPg[h] + sPb[h], 0.f);
            aph[j] = (_Float16)v;
        }
#pragma unroll
        for (int f = 0; f < 4; f++) {
            f16x4 bP;
#pragma unroll
            for (int j = 0; j < 4; j++)
                bP[j] = (_Float16)Wp2[(g * 4 + j) * 64 + f * 16 + col];
            f32x4 cini;
#pragma unroll
            for (int r = 0; r < 4; r++) cini[r] = bp2c[f];
            pr[f] = __builtin_amdgcn_mfma_f32_16x16x16f16(aph, bP, cini,
                                                          0, 0, 0);
        }
    }
#else
    {
        f16x8 aph;
#pragma unroll
        for (int j = 0; j < 8; j++) {
            int h = g * 8 + j;
            float v = 0.f;
            if (g < 2) {
                v = px * sWp1[h] + py * sWp1[16 + h] + pz * sWp1[32 + h];
                v = fmaxf(v * sPg[h] + sPb[h], 0.f);
            }
            aph[j] = (_Float16)v;
        }
#pragma unroll
        for (int f = 0; f < 4; f++) {
            f16x8 bP;
#pragma unroll
            for (int j = 0; j < 8; j++) {
                int h = g * 8 + j;
                bP[j] = (g < 2) ? (_Float16)Wp2[h * 64 + f * 16 + col]
                                : (_Float16)0.f;
            }
            f32x4 cini;
#pragma unroll
            for (int r = 0; r < 4; r++) cini[r] = bp2c[f];
            pr[f] = __builtin_amdgcn_mfma_f32_16x16x32_f16(aph, bP, cini,
                                                           0, 0, 0);
        }
    }
#endif
    // ---- GEMM1, K-chunked through 16x40 scr ----
    f32x4 acc1[8];
#pragma unroll
    for (int f = 0; f < 8; f++)
#pragma unroll
        for (int r = 0; r < 4; r++) acc1[f][r] = 0.f;
#pragma unroll
    for (int kc = 0; kc < 2; kc++) {
#pragma unroll
        for (int fp = 0; fp < 2; fp++) {
            int f = kc * 2 + fp;
#pragma unroll
            for (int r = 0; r < 4; r++) {
                float w0 = xkv[r][f] - xqv[f] + pr[f][r];
                float uu = fmaxf(w0 * g1c[f] + b1c[f], 0.f);
                scr[(g * 4 + r) * 40 + fp * 16 + col] = (_Float16)uu;
            }
        }
        f16x8 au = *(const f16x8*)&scr[col * 40 + g * 8];
#pragma unroll
        for (int f = 0; f < 8; f++) {
            f16x8 bw = *(const f16x8*)
                &sW1t[(f * 16 + col) * 72 + kc * 32 + g * 8];
            acc1[f] = __builtin_amdgcn_mfma_f32_16x16x32_f16(au, bw, acc1[f],
                                                             0, 0, 0);
        }
    }
    // ---- o1 epilogue to f16 regs (frees acc1) ----
    _Float16 o1v[8][4];
#pragma unroll
    for (int f = 0; f < 8; f++) {
        float gn = sg2[f * 16 + col], bs = sb2[f * 16 + col];
#pragma unroll
        for (int r = 0; r < 4; r++)
            o1v[f][r] = (_Float16)fmaxf(acc1[f][r] * gn + bs, 0.f);
    }
    __syncthreads();  // barrier 3: sW2t restaged
    // ---- GEMM2, K-chunked (bw2 dropped: cancels in softmax over s) ----
    f32x4 accL[4];
#pragma unroll
    for (int f = 0; f < 4; f++)
#pragma unroll
        for (int r = 0; r < 4; r++) accL[f][r] = 0.f;
#pragma unroll
    for (int c = 0; c < 4; c++) {
#pragma unroll
        for (int fp = 0; fp < 2; fp++)
#pragma unroll
            for (int r = 0; r < 4; r++)
                scr[(g * 4 + r) * 40 + fp * 16 + col] = o1v[c * 2 + fp][r];
        f16x8 ao = *(const f16x8*)&scr[col * 40 + g * 8];
#pragma unroll
        for (int f = 0; f < 4; f++) {
            f16x8 bw = *(const f16x8*)
                &sW2t[(f * 16 + col) * 136 + c * 32 + g * 8];
            accL[f] = __builtin_amdgcn_mfma_f32_16x16x32_f16(ao, bw, accL[f],
                                                             0, 0, 0);
        }
    }
    // ---- DEFERRED xvv gather (acc1/o1v dead; live set small) ----
    float xvv[4][4];
#pragma unroll
    for (int r = 0; r < 4; r++)
#pragma unroll
        for (int f = 0; f < 4; f++)
            xvv[r][f] = xv[jr[r] * 64 + f * 16 + col];
    // ---- softmax over s + einsum (vvr folded: xvv + pr inline) ----
    float outv[4];
#pragma unroll
    for (int f = 0; f < 4; f++) {
        float mx = fmaxf(fmaxf(accL[f][0], accL[f][1]),
                         fmaxf(accL[f][2], accL[f][3]));
        mx = fmaxf(mx, __shfl_xor(mx, 16, 64));
        mx = fmaxf(mx, __shfl_xor(mx, 32, 64));
        float sum = 0.f, part = 0.f;
#pragma unroll
        for (int r = 0; r < 4; r++) {
            float e = __expf(accL[f][r] - mx);
            sum += e;
            part = fmaf(e, xvv[r][f] + pr[f][r], part);
        }
        sum += __shfl_xor(sum, 16, 64);
        sum += __shfl_xor(sum, 32, 64);
        part += __shfl_xor(part, 16, 64);
        part += __shfl_xor(part, 32, 64);
        outv[f] = part / sum;
    }
    float val = (g == 0) ? outv[0]
              : (g == 1) ? outv[1]
              : (g == 2) ? outv[2] : outv[3];
    attn[q * 64 + lane] = val;
}

// ---------------------------------------------------------------------------
// K3: FUSED MFMA-f16 head (verbatim — protected).
// ---------------------------------------------------------------------------
__global__ __launch_bounds__(256) void head_kernel(
    const float* __restrict__ feats, const float* __restrict__ attn,
    const _Float16* __restrict__ Wc1tG, const float* __restrict__ cg1,
    const float* __restrict__ cb1, const _Float16* __restrict__ Wc2tG,
    const float* __restrict__ cg2, const float* __restrict__ cb2,
    const _Float16* __restrict__ Wc3tG, const float* __restrict__ bc3,
    const float* __restrict__ lng, const float* __restrict__ lnb,
    float* __restrict__ out)
{
    __shared__ _Float16 sWt[128 * 136];
    __shared__ _Float16 sX[16 * 136];
    __shared__ _Float16 sY[16 * 136];
    __shared__ float sOut[16 * 68];
    __shared__ float sga[128], sba[128], sgb[128], sbb[128];
    __shared__ float sbc3[64], slng[64], slnb[64];

    const int t = threadIdx.x;
    const int lane = t & 63;
    const int wv = t >> 6;  // 0..3
    const int col = lane & 15, g = lane >> 4;
    const int row0 = blockIdx.x * 16;

    {
        int r = t >> 4, c0 = (t & 15) * 8;
        const float* src = (c0 < 64) ? (feats + (row0 + r) * 64 + c0)
                                     : (attn + (row0 + r) * 64 + (c0 - 64));
        float4 v0 = ((const float4*)src)[0];
        float4 v1 = ((const float4*)src)[1];
        _Float16* dst = &sX[r * 136 + c0];
        dst[0] = (_Float16)v0.x; dst[1] = (_Float16)v0.y;
        dst[2] = (_Float16)v0.z; dst[3] = (_Float16)v0.w;
        dst[4] = (_Float16)v1.x; dst[5] = (_Float16)v1.y;
        dst[6] = (_Float16)v1.z; dst[7] = (_Float16)v1.w;
    }
    auto stageWT = [&](const _Float16* WT, int chunks) {
        for (int i = t; i < chunks; i += 256) {
            int n = i >> 4, ko = i & 15;
            *(f16x8*)&sWt[n * 136 + ko * 8] =
                *(const f16x8*)&WT[n * 128 + ko * 8];
        }
    };
    stageWT(Wc1tG, 2048);
    if (t < 128) {
        sga[t] = cg1[t] * BN_INV; sba[t] = cb1[t];
        sgb[t] = cg2[t] * BN_INV; sbb[t] = cb2[t];
    } else if (t < 192) {
        int o = t - 128;
        sbc3[o] = bc3[o]; slng[o] = lng[o]; slnb[o] = lnb[o];
    }
    __syncthreads();
    // L1: 16x128 = 8 col-tiles; wave wv covers cols wv*32..wv*32+31
    {
        f16x8 ax[4];
#pragma unroll
        for (int kc = 0; kc < 4; kc++)
            ax[kc] = *(const f16x8*)&sX[col * 136 + kc * 32 + g * 8];
#pragma unroll
        for (int ft = 0; ft < 2; ft++) {
            int n = wv * 32 + ft * 16 + col;
            f32x4 acc;
#pragma unroll
            for (int r = 0; r < 4; r++) acc[r] = 0.f;
#pragma unroll
            for (int kc = 0; kc < 4; kc++) {
                f16x8 bw = *(const f16x8*)&sWt[n * 136 + kc * 32 + g * 8];
                acc = __builtin_amdgcn_mfma_f32_16x16x32_f16(ax[kc], bw, acc,
                                                             0, 0, 0);
            }
            float gn = sga[n], bs = sba[n];
#pragma unroll
            for (int r = 0; r < 4; r++)
                sY[(g * 4 + r) * 136 + n] =
                    (_Float16)fmaxf(acc[r] * gn + bs, 0.f);
        }
    }
    __syncthreads();
    stageWT(Wc2tG, 2048);
    __syncthreads();
    // L2: sY -> sX
    {
        f16x8 ax[4];
#pragma unroll
        for (int kc = 0; kc < 4; kc++)
            ax[kc] = *(const f16x8*)&sY[col * 136 + kc * 32 + g * 8];
#pragma unroll
        for (int ft = 0; ft < 2; ft++) {
            int n = wv * 32 + ft * 16 + col;
            f32x4 acc;
#pragma unroll
            for (int r = 0; r < 4; r++) acc[r] = 0.f;
#pragma unroll
            for (int kc = 0; kc < 4; kc++) {
                f16x8 bw = *(const f16x8*)&sWt[n * 136 + kc * 32 + g * 8];
                acc = __builtin_amdgcn_mfma_f32_16x16x32_f16(ax[kc], bw, acc,
                                                             0, 0, 0);
            }
            float gn = sgb[n], bs = sbb[n];
#pragma unroll
            for (int r = 0; r < 4; r++)
                sX[(g * 4 + r) * 136 + n] =
                    (_Float16)fmaxf(acc[r] * gn + bs, 0.f);
        }
    }
    __syncthreads();
    stageWT(Wc3tG, 1024);
    __syncthreads();
    // L3: 16x64; wave wv covers cols wv*16..wv*16+15
    {
        f16x8 ax[4];
#pragma unroll
        for (int kc = 0; kc < 4; kc++)
            ax[kc] = *(const f16x8*)&sX[col * 136 + kc * 32 + g * 8];
        int n = wv * 16 + col;
        f32x4 acc;
        float bias = sbc3[n];
#pragma unroll
        for (int r = 0; r < 4; r++) acc[r] = bias;
#pragma unroll
        for (int kc = 0; kc < 4; kc++) {
            f16x8 bw = *(const f16x8*)&sWt[n * 136 + kc * 32 + g * 8];
            acc = __builtin_amdgcn_mfma_f32_16x16x32_f16(ax[kc], bw, acc,
                                                         0, 0, 0);
        }
#pragma unroll
        for (int r = 0; r < 4; r++)
            sOut[(g * 4 + r) * 68 + n] = acc[r];
    }
    __syncthreads();
    // LN epilogue: r = t>>4, 16 lanes per row, width-16 shuffle
    {
        int r = t >> 4, o0 = (t & 15) * 4;
        float v[4];
        float s1 = 0.f, s2 = 0.f;
#pragma unroll
        for (int k = 0; k < 4; k++) {
            v[k] = sOut[r * 68 + o0 + k];
            s1 += v[k];
            s2 = fmaf(v[k], v[k], s2);
        }
#pragma unroll
        for (int d = 1; d < 16; d <<= 1) {
            s1 += __shfl_xor(s1, d, 16);
            s2 += __shfl_xor(s2, d, 16);
        }
        float m = s1 * (1.f / 64.f);
        float var = s2 * (1.f / 64.f) - m * m;
        float inv = 1.f / sqrtf(var + LN_EPS);
        float* dst = out + (row0 + r) * 64;
#pragma unroll
        for (int k = 0; k < 4; k++) {
            int o = o0 + k;
            dst[o] = (v[k] - m) * inv * slng[o] + slnb[o];
        }
    }
}

// ---------------------------------------------------------------------------
extern "C" void kernel_launch(void* const* d_in, const int* in_sizes, int n_in,
                              void* d_out, int out_size, void* d_ws,
                              size_t ws_size, hipStream_t stream)
{
    const int* indices = (const int*)d_in[0];
    const float* feats = (const float*)d_in[1];
    const float* Wq = (const float*)d_in[2];
    const float* bq = (const float*)d_in[3];
    const float* Wk = (const float*)d_in[4];
    const float* bk = (const float*)d_in[5];
    const float* Wv = (const float*)d_in[6];
    const float* bv = (const float*)d_in[7];
    const float* Wp1 = (const float*)d_in[8];
    const float* pg = (const float*)d_in[9];
    const float* pb = (const float*)d_in[10];
    const float* Wp2 = (const float*)d_in[11];
    const float* bp2 = (const float*)d_in[12];
    const float* wg1 = (const float*)d_in[13];
    const float* wb1 = (const float*)d_in[14];
    const float* Ww1 = (const float*)d_in[15];
    const float* wg2 = (const float*)d_in[16];
    const float* wb2 = (const float*)d_in[17];
    const float* Ww2 = (const float*)d_in[18];
    const float* Wc1 = (const float*)d_in[20];
    const float* cg1 = (const float*)d_in[21];
    const float* cb1 = (const float*)d_in[22];
    const float* Wc2 = (const float*)d_in[23];
    const float* cg2 = (const float*)d_in[24];
    const float* cb2 = (const float*)d_in[25];
    const float* Wc3 = (const float*)d_in[26];
    const float* bc3 = (const float*)d_in[27];
    const float* lng = (const float*)d_in[28];
    const float* lnb = (const float*)d_in[29];

    float* out = (float*)d_out;
    float* ws = (float*)d_ws;
    float* xq = ws;
    float* xk = xq + N * C;
    float* xv = xk + N * C;
    float* attn = xv + N * C;
    int* knn = (int*)(attn + N * C);   // unused now; layout kept
    _Float16* wt16 = (_Float16*)(knn + N * 16);
    _Float16* W1tG = wt16;              // 128 x 64
    _Float16* W2tG = W1tG + 8192;       // 64 x 128
    _Float16* Wc1tG = W2tG + 8192;      // 128 x 128
    _Float16* Wc2tG = Wc1tG + 16384;    // 128 x 128
    _Float16* Wc3tG = Wc2tG + 16384;    // 64 x 128
    // x-sorted point array (16B-aligned) + 768-entry slack for prefetch /
    // staging / batched-fallback over-reads (values masked), then cdf[129].
    uint2* sortedG = (uint2*)(Wc3tG + 8192);
    int* cdfG = (int*)(sortedG + 8192 + 768);

    prep_kernel<<<70, 512, 32768, stream>>>(
        (const int4*)indices, feats, Wq, bq, Wk, bk, Wv, bv, xq, xk, xv,
        Ww1, Ww2, Wc1, Wc2, Wc3, W1tG, W2tG, Wc1tG, Wc2tG, Wc3tG,
        sortedG, cdfG);
    knnattn_kernel<<<1024, 512, 0, stream>>>(
        (const int4*)indices, sortedG, cdfG, xq, xk, xv, Wp1, pg, pb, Wp2,
        bp2, wg1, wb1, W1tG, wg2, wb2, W2tG, attn);
    head_kernel<<<512, 256, 0, stream>>>(feats, attn, Wc1tG, cg1, cb1, Wc2tG,
                                         cg2, cb2, Wc3tG, bc3, lng, lnb, out);
}

// Round 14
// 159.211 us; speedup vs baseline: 1.0321x; 1.0321x over previous
//
#include <hip/hip_runtime.h>

// ============================================================================
// ROUND 14 — REVERT TO BANKED BEST (r12, 160.9us). r13's LDS-slab staging
// regressed (+3.4us): the scan was not L2-contention-bound; the serial
// per-block staging prologue + 2 extra barriers cost more than the latency
// they removed (same lesson as r7: in a latency-bound kernel with all
// blocks co-resident, serialized phases are paid in full).
// This is r12 byte-identical: prep (5-way split, coalesced-read
// transposes) + knnattn (merged, de-spilled, (512,6) = 3 blocks/CU) +
// head. Session fixes banked: slab-pruned exact KNN (r2), merge (r7),
// de-spill via deferred xvv (r10), 3rd block via (512,6) (r11),
// transpose orientation + split (r12).
// ============================================================================

#define N 8192
#define C 64
#define S 16

static constexpr float BN_INV = 0.9999950000374997f; // 1/sqrt(1+1e-5)
static constexpr float LN_EPS = 1e-5f;

typedef _Float16 f16x8 __attribute__((ext_vector_type(8)));
typedef _Float16 f16x4 __attribute__((ext_vector_type(4)));
typedef float f32x4 __attribute__((ext_vector_type(4)));

__device__ __forceinline__ void sort2(unsigned& x, unsigned& y)
{
    unsigned lo = min(x, y);
    unsigned hi = max(x, y);
    x = lo;
    y = hi;
}

__device__ __forceinline__ unsigned med3u(unsigned a, unsigned b, unsigned c)
{
    unsigned r;
    asm("v_med3_u32 %0, %1, %2, %3" : "=v"(r) : "v"(a), "v"(b), "v"(c));
    return r;
}

__device__ __forceinline__ void insert4(unsigned& a0, unsigned& a1,
                                        unsigned& a2, unsigned& a3,
                                        unsigned k)
{
    unsigned m = min(a3, k);
    unsigned n1 = med3u(a0, a1, m);
    unsigned n2 = med3u(a1, a2, m);
    a3 = max(a2, m);
    a0 = min(a0, m);
    a1 = n1;
    a2 = n2;
}

__device__ __forceinline__ int mbcnt64(unsigned long long m)
{
    int lo = __builtin_amdgcn_mbcnt_lo((unsigned)m, 0);
    return __builtin_amdgcn_mbcnt_hi((unsigned)(m >> 32), lo);
}

// d2 from packed coords (x|y<<8|z<<16, byte3 = 0).
__device__ __forceinline__ unsigned d2_packed(unsigned pk, unsigned qq,
                                              unsigned qpk2, int qx, int qy,
                                              int qz)
{
#if __has_builtin(__builtin_amdgcn_udot4)
    return __builtin_amdgcn_udot4(pk, pk, qq, false) -
           __builtin_amdgcn_udot4(pk, qpk2, 0u, false);
#else
    int x = (int)(pk & 255u), y = (int)((pk >> 8) & 255u),
        z = (int)((pk >> 16) & 255u);
    int dx = x - qx, dy = y - qy, dz = z - qz;
    (void)qpk2;
    return (unsigned)(dx * dx + dy * dy + dz * dz);
#endif
}

// ---------------------------------------------------------------------------
// K0: PREP — blocks 0..63: qkv GEMM; block 64: counting sort by x; blocks
// 65..69: one weight transpose each, coalesced float4 input reads +
// scattered writes.
// ---------------------------------------------------------------------------
__global__ __launch_bounds__(512) void prep_kernel(
    const int4* __restrict__ idx4, const float* __restrict__ feats,
    const float* __restrict__ Wq, const float* __restrict__ bq,
    const float* __restrict__ Wk, const float* __restrict__ bk,
    const float* __restrict__ Wv, const float* __restrict__ bv,
    float* __restrict__ xq, float* __restrict__ xk, float* __restrict__ xv,
    const float* __restrict__ Ww1, const float* __restrict__ Ww2,
    const float* __restrict__ Wc1, const float* __restrict__ Wc2,
    const float* __restrict__ Wc3,
    _Float16* __restrict__ W1tG, _Float16* __restrict__ W2tG,
    _Float16* __restrict__ Wc1tG, _Float16* __restrict__ Wc2tG,
    _Float16* __restrict__ Wc3tG,
    uint2* __restrict__ sorted, int* __restrict__ cdf)
{
    extern __shared__ char smem[];
    const int t = threadIdx.x;
    const int lane = t & 63;
    const int wv = t >> 6;
    const int bx = blockIdx.x;
    if (bx == 64) {
        // ---------------- counting sort by x ----------------
        __shared__ int whist[8][128];
        __shared__ int wrun[8][128];
        __shared__ int tot[128];
        __shared__ int binbase[128];
        for (int i = t; i < 1024; i += 512) ((int*)whist)[i] = 0;
        __syncthreads();
        int4 c[16];
#pragma unroll
        for (int i = 0; i < 16; i++) c[i] = idx4[i * 512 + t];
#pragma unroll
        for (int i = 0; i < 16; i++) atomicAdd(&whist[wv][c[i].y], 1);
        __syncthreads();
        if (t < 128) {
            int acc = 0;
#pragma unroll
            for (int w = 0; w < 8; w++) {
                wrun[w][t] = acc;
                acc += whist[w][t];
            }
            tot[t] = acc;
        }
        __syncthreads();
        if (t < 64) {
            int h0 = tot[2 * t], h1 = tot[2 * t + 1];
            int s = h0 + h1;
            int incl = s;
#pragma unroll
            for (int d = 1; d < 64; d <<= 1) {
                int nb = __shfl_up(incl, d, 64);
                if (t >= d) incl += nb;
            }
            int excl = incl - s;
            binbase[2 * t] = excl;
            binbase[2 * t + 1] = excl + h0;
            cdf[2 * t] = excl;
            cdf[2 * t + 1] = excl + h0;
            if (t == 63) cdf[128] = 8192;
        }
        __syncthreads();
        if (t < 128) {
            int bb = binbase[t];
#pragma unroll
            for (int w = 0; w < 8; w++) wrun[w][t] += bb;
        }
        __syncthreads();
#pragma unroll
        for (int i = 0; i < 16; i++) {
            int4 cc = c[i];
            unsigned pk = (unsigned)cc.y | ((unsigned)cc.z << 8) |
                          ((unsigned)cc.w << 16);
            int pos = atomicAdd(&wrun[wv][cc.y], 1);
            sorted[pos] = make_uint2(pk, (unsigned)(i * 512 + t));
        }
    } else if (bx < 64) {
        // ---------------- qkv GEMM (verbatim) ----------------
        _Float16* sBt = (_Float16*)smem;
        float* sbias = (float*)(smem + 192 * 72 * 2);
        const int col = lane & 15, g = lane >> 4;
        const int row0w = bx * 128 + wv * 16;
        {
            const float* Ws[3] = {Wq, Wk, Wv};
#pragma unroll
            for (int m = 0; m < 3; m++) {
                int k = t >> 3, nb = (t & 7) * 8;
                const float4* src = (const float4*)(Ws[m] + k * 64 + nb);
                float4 w0 = src[0], w1 = src[1];
                _Float16* dst = &sBt[(m * 64 + nb) * 72 + k];
                dst[0 * 72] = (_Float16)w0.x; dst[1 * 72] = (_Float16)w0.y;
                dst[2 * 72] = (_Float16)w0.z; dst[3 * 72] = (_Float16)w0.w;
                dst[4 * 72] = (_Float16)w1.x; dst[5 * 72] = (_Float16)w1.y;
                dst[6 * 72] = (_Float16)w1.z; dst[7 * 72] = (_Float16)w1.w;
            }
            if (t < 64) sbias[t] = bq[t];
            else if (t < 128) sbias[t] = bk[t - 64];
            else if (t < 192) sbias[t] = bv[t - 128];
        }
        __syncthreads();
        f16x8 au[2];
#pragma unroll
        for (int kc = 0; kc < 2; kc++) {
            const float4* src = (const float4*)
                (feats + (row0w + col) * 64 + kc * 32 + g * 8);
            float4 v0 = src[0], v1 = src[1];
            au[kc][0] = (_Float16)v0.x; au[kc][1] = (_Float16)v0.y;
            au[kc][2] = (_Float16)v0.z; au[kc][3] = (_Float16)v0.w;
            au[kc][4] = (_Float16)v1.x; au[kc][5] = (_Float16)v1.y;
            au[kc][6] = (_Float16)v1.z; au[kc][7] = (_Float16)v1.w;
        }
        float* outs[3] = {xq, xk, xv};
#pragma unroll
        for (int f = 0; f < 12; f++) {
            f32x4 acc;
            float bias = sbias[f * 16 + col];
#pragma unroll
            for (int r = 0; r < 4; r++) acc[r] = bias;
#pragma unroll
            for (int kc = 0; kc < 2; kc++) {
                f16x8 bw = *(const f16x8*)
                    &sBt[(f * 16 + col) * 72 + kc * 32 + g * 8];
                acc = __builtin_amdgcn_mfma_f32_16x16x32_f16(au[kc], bw, acc,
                                                             0, 0, 0);
            }
            float* o = outs[f >> 2];
            int cg = (f & 3) * 16 + col;
#pragma unroll
            for (int r = 0; r < 4; r++)
                o[(row0w + g * 4 + r) * 64 + cg] = acc[r];
        }
    } else if (bx == 65) {
        // W1tG[n*64+k] = Ww1[k*128+n]; Ww1 64x128. Coalesced input reads.
        for (int i4 = t; i4 < 2048; i4 += 512) {
            const float4 v = ((const float4*)Ww1)[i4];
            const int j = i4 * 4, k = j >> 7, n = j & 127;
            W1tG[(n + 0) * 64 + k] = (_Float16)v.x;
            W1tG[(n + 1) * 64 + k] = (_Float16)v.y;
            W1tG[(n + 2) * 64 + k] = (_Float16)v.z;
            W1tG[(n + 3) * 64 + k] = (_Float16)v.w;
        }
    } else if (bx == 66) {
        // W2tG[n*128+k] = Ww2[k*64+n]; Ww2 128x64.
        for (int i4 = t; i4 < 2048; i4 += 512) {
            const float4 v = ((const float4*)Ww2)[i4];
            const int j = i4 * 4, k = j >> 6, n = j & 63;
            W2tG[(n + 0) * 128 + k] = (_Float16)v.x;
            W2tG[(n + 1) * 128 + k] = (_Float16)v.y;
            W2tG[(n + 2) * 128 + k] = (_Float16)v.z;
            W2tG[(n + 3) * 128 + k] = (_Float16)v.w;
        }
    } else if (bx == 67) {
        // Wc1tG[n*128+k] = Wc1[k*128+n]; Wc1 128x128.
        for (int i4 = t; i4 < 4096; i4 += 512) {
            const float4 v = ((const float4*)Wc1)[i4];
            const int j = i4 * 4, k = j >> 7, n = j & 127;
            Wc1tG[(n + 0) * 128 + k] = (_Float16)v.x;
            Wc1tG[(n + 1) * 128 + k] = (_Float16)v.y;
            Wc1tG[(n + 2) * 128 + k] = (_Float16)v.z;
            Wc1tG[(n + 3) * 128 + k] = (_Float16)v.w;
        }
    } else if (bx == 68) {
        // Wc2tG[n*128+k] = Wc2[k*128+n]; Wc2 128x128.
        for (int i4 = t; i4 < 4096; i4 += 512) {
            const float4 v = ((const float4*)Wc2)[i4];
            const int j = i4 * 4, k = j >> 7, n = j & 127;
            Wc2tG[(n + 0) * 128 + k] = (_Float16)v.x;
            Wc2tG[(n + 1) * 128 + k] = (_Float16)v.y;
            Wc2tG[(n + 2) * 128 + k] = (_Float16)v.z;
            Wc2tG[(n + 3) * 128 + k] = (_Float16)v.w;
        }
    } else {
        // Wc3tG[n*128+k] = Wc3[k*64+n]; Wc3 128x64.
        for (int i4 = t; i4 < 2048; i4 += 512) {
            const float4 v = ((const float4*)Wc3)[i4];
            const int j = i4 * 4, k = j >> 6, n = j & 63;
            Wc3tG[(n + 0) * 128 + k] = (_Float16)v.x;
            Wc3tG[(n + 1) * 128 + k] = (_Float16)v.y;
            Wc3tG[(n + 2) * 128 + k] = (_Float16)v.z;
            Wc3tG[(n + 3) * 128 + k] = (_Float16)v.w;
        }
    }
}

// ---------------------------------------------------------------------------
// K1: MERGED knn+attn — de-spilled body (xvv deferred past GEMM2, vvr
// folded), (512,6) cap, 3 blocks/CU.
// ---------------------------------------------------------------------------
__global__ __launch_bounds__(512, 6) void knnattn_kernel(
    const int4* __restrict__ idx4, const uint2* __restrict__ sorted,
    const int* __restrict__ cdf,
    const float* __restrict__ xq, const float* __restrict__ xk,
    const float* __restrict__ xv,
    const float* __restrict__ Wp1, const float* __restrict__ pg,
    const float* __restrict__ pb, const float* __restrict__ Wp2,
    const float* __restrict__ bp2,
    const float* __restrict__ wg1, const float* __restrict__ wb1,
    const _Float16* __restrict__ W1tG,
    const float* __restrict__ wg2, const float* __restrict__ wb2,
    const _Float16* __restrict__ W2tG,
    float* __restrict__ attn)
{
    __shared__ _Float16 sW1t[128 * 72];    // 18.0 KB
    __shared__ _Float16 sW2t[64 * 136];    // 17.0 KB
    __shared__ _Float16 sscr[8][16 * 40];  // 10.0 KB (per-wave 16x40)
    __shared__ int sKnn[8][16];            // 0.5 KB per-wave knn handoff
    __shared__ float sWp1[48], sPg[16], sPb[16];
    __shared__ float sg2[128], sb2[128];

    const int t = threadIdx.x;
    const int lane = t & 63;
    const int wv = t >> 6;
    const int col = lane & 15, g = lane >> 4;

    // ---- weight staging: issue loads now, barrier AFTER the knn phase ----
    for (int i = t; i < 1024; i += 512) {
        int n = i >> 3, ko = i & 7;
        *(f16x8*)&sW1t[n * 72 + ko * 8] =
            *(const f16x8*)&W1tG[n * 64 + ko * 8];
    }
    for (int i = t; i < 1024; i += 512) {
        int m = i >> 4, ko = i & 15;
        *(f16x8*)&sW2t[m * 136 + ko * 8] =
            *(const f16x8*)&W2tG[m * 128 + ko * 8];
    }
    if (t < 48) sWp1[t] = Wp1[t];
    if (t < 16) { sPg[t] = pg[t] * BN_INV; sPb[t] = pb[t]; }
    if (t >= 64 && t < 192) {
        int o = t - 64;
        sg2[o] = wg2[o] * BN_INV;
        sb2[o] = wb2[o];
    }
    float g1c[4], b1c[4], bp2c[4];
#pragma unroll
    for (int f = 0; f < 4; f++) {
        int c = f * 16 + col;
        g1c[f] = wg1[c] * BN_INV; b1c[f] = wb1[c];
        bp2c[f] = bp2[c];
    }

    // ---- query identity + earliest possible xq gather ----
    const int pos = blockIdx.x * 8 + wv;
    const uint2 sq = sorted[pos];
    const int q = (int)sq.y;
    const int qx = (int)(sq.x & 255u);
    const int qy = (int)((sq.x >> 8) & 255u);
    const int qz = (int)(sq.x >> 16);
    float xqv[4];
#pragma unroll
    for (int f = 0; f < 4; f++) xqv[f] = xq[q * 64 + f * 16 + col];

    // ---- phase 1: per-wave KNN (registers/ballots only) ----
    {
        const unsigned qq = (unsigned)(qx * qx + qy * qy + qz * qz);
#if __has_builtin(__builtin_amdgcn_udot4)
        const unsigned qpk2 = (unsigned)(2 * qx) |
                              ((unsigned)(2 * qy) << 8) |
                              ((unsigned)(2 * qz) << 16);
#else
        const unsigned qpk2 = 0;
#endif
        const int lo = (qx > 18) ? qx - 18 : 0;
        const int hi = (qx < 109) ? qx + 18 : 127;
        const int start = cdf[lo];
        const int end = cdf[hi + 1];
        const int nc = end - start;
        const int s0 = start & ~1;                // 16B-align uint4 loads
        const int iters = (end - s0 + 255) >> 8;  // 256 cands/wave/iter

        unsigned a0 = 0xFFFFFFFFu, a1 = 0xFFFFFFFFu, a2 = 0xFFFFFFFFu,
                 a3 = 0xFFFFFFFFu;
        unsigned b0 = 0xFFFFFFFFu, b1 = 0xFFFFFFFFu, b2 = 0xFFFFFFFFu,
                 b3 = 0xFFFFFFFFu;
        uint4 cd0 = *(const uint4*)(sorted + s0 + lane * 2);
        uint4 cd1 = *(const uint4*)(sorted + s0 + lane * 2 + 128);
        for (int ii = 0; ii < iters; ++ii) {
            const int j0 = s0 + ii * 256 + lane * 2;
            const int j1 = j0 + 128;
            const uint4 nx0 = *(const uint4*)(sorted + j0 + 256);
            const uint4 nx1 = *(const uint4*)(sorted + j0 + 384);
            unsigned d00 = d2_packed(cd0.x, qq, qpk2, qx, qy, qz);
            unsigned d01 = d2_packed(cd0.z, qq, qpk2, qx, qy, qz);
            unsigned d10 = d2_packed(cd1.x, qq, qpk2, qx, qy, qz);
            unsigned d11 = d2_packed(cd1.z, qq, qpk2, qx, qy, qz);
            unsigned k00 = (j0 >= start && j0 < end) ? (d00 << 13) + cd0.y
                                                     : 0xFFFFFFFFu;
            unsigned k01 = (j0 + 1 < end) ? (d01 << 13) + cd0.w
                                          : 0xFFFFFFFFu;
            unsigned k10 = (j1 < end) ? (d10 << 13) + cd1.y : 0xFFFFFFFFu;
            unsigned k11 = (j1 + 1 < end) ? (d11 << 13) + cd1.w
                                          : 0xFFFFFFFFu;
            insert4(a0, a1, a2, a3, k00);
            insert4(a0, a1, a2, a3, k10);
            insert4(b0, b1, b2, b3, k01);
            insert4(b0, b1, b2, b3, k11);
            cd0 = nx0;
            cd1 = nx1;
        }
        const unsigned LIM = 1u << 22;
        int c_all = __popcll(__ballot(a0 < LIM)) +
                    __popcll(__ballot(a1 < LIM)) +
                    __popcll(__ballot(a2 < LIM)) +
                    __popcll(__ballot(a3 < LIM)) +
                    __popcll(__ballot(b0 < LIM)) +
                    __popcll(__ballot(b1 < LIM)) +
                    __popcll(__ballot(b2 < LIM)) +
                    __popcll(__ballot(b3 < LIM));
        const bool deep = (c_all >= 16);
        unsigned prefix = 0u;
#pragma unroll
        for (int bit = 21; bit >= 0; --bit) {
            unsigned cand = prefix | (1u << bit);
            int c = __popcll(__ballot(a0 < cand)) +
                    __popcll(__ballot(a1 < cand)) +
                    __popcll(__ballot(a2 < cand)) +
                    __popcll(__ballot(a3 < cand)) +
                    __popcll(__ballot(b0 < cand)) +
                    __popcll(__ballot(b1 < cand)) +
                    __popcll(__ballot(b2 < cand)) +
                    __popcll(__ballot(b3 < cand));
            if (c < 16) prefix = cand;
        }
        const unsigned T = prefix;
        {
            unsigned long long m0 = __ballot(a0 <= T);
            unsigned long long m1 = __ballot(a1 <= T);
            unsigned long long m2 = __ballot(a2 <= T);
            unsigned long long m3 = __ballot(a3 <= T);
            unsigned long long m4 = __ballot(b0 <= T);
            unsigned long long m5 = __ballot(b1 <= T);
            unsigned long long m6 = __ballot(b2 <= T);
            unsigned long long m7 = __ballot(b3 <= T);
            int p1 = __popcll(m0);
            int p2 = p1 + __popcll(m1);
            int p3 = p2 + __popcll(m2);
            int p4 = p3 + __popcll(m3);
            int p5 = p4 + __popcll(m4);
            int p6 = p5 + __popcll(m5);
            int p7 = p6 + __popcll(m6);
            int* dst = sKnn[wv];
            if (a0 <= T) dst[mbcnt64(m0)] = (int)(a0 & 8191u);
            if (a1 <= T) dst[p1 + mbcnt64(m1)] = (int)(a1 & 8191u);
            if (a2 <= T) dst[p2 + mbcnt64(m2)] = (int)(a2 & 8191u);
            if (a3 <= T) dst[p3 + mbcnt64(m3)] = (int)(a3 & 8191u);
            if (b0 <= T) dst[p4 + mbcnt64(m4)] = (int)(b0 & 8191u);
            if (b1 <= T) dst[p5 + mbcnt64(m5)] = (int)(b1 & 8191u);
            if (b2 <= T) dst[p6 + mbcnt64(m6)] = (int)(b2 & 8191u);
            if (b3 <= T) dst[p7 + mbcnt64(m7)] = (int)(b3 & 8191u);
        }
        const unsigned d2T = T >> 13;
        unsigned long long badm = __ballot(a3 < T) | __ballot(b3 < T);
        if (!deep || badm != 0ull || d2T > 324u || nc < 16) {
            int R2 = deep ? min(127, (int)sqrtf((float)d2T) + 1) : 127;
            if (nc < 16) R2 = 127;
            const int lo2 = (qx > R2) ? qx - R2 : 0;
            const int hi2 = (qx + R2 < 127) ? qx + R2 : 127;
            const int sF = cdf[lo2];
            const int eF = cdf[hi2 + 1];
            const int sA = sF & ~3;                   // 16B alignment
            const int itF = (eF - sA + 255) >> 8;     // 4 cands/lane/iter
            unsigned c0 = 0xFFFFFFFFu, c1 = 0xFFFFFFFFu, c2 = 0xFFFFFFFFu,
                     c3 = 0xFFFFFFFFu, c4 = 0xFFFFFFFFu, c5 = 0xFFFFFFFFu,
                     c6 = 0xFFFFFFFFu, c7 = 0xFFFFFFFFu, c8 = 0xFFFFFFFFu,
                     c9 = 0xFFFFFFFFu, c10 = 0xFFFFFFFFu, c11 = 0xFFFFFFFFu,
                     c12 = 0xFFFFFFFFu, c13 = 0xFFFFFFFFu, c14 = 0xFFFFFFFFu,
                     c15 = 0xFFFFFFFFu;
            for (int ii = 0; ii < itF; ++ii) {
                const int jb = sA + ii * 256 + lane * 4;
                const uint4 w0 = *(const uint4*)(sorted + jb);
                const uint4 w1 = *(const uint4*)(sorted + jb + 2);
                unsigned kk[4];
                kk[0] = (jb >= sF && jb < eF)
                    ? (d2_packed(w0.x, qq, qpk2, qx, qy, qz) << 13) + w0.y
                    : 0xFFFFFFFFu;
                kk[1] = (jb + 1 >= sF && jb + 1 < eF)
                    ? (d2_packed(w0.z, qq, qpk2, qx, qy, qz) << 13) + w0.w
                    : 0xFFFFFFFFu;
                kk[2] = (jb + 2 >= sF && jb + 2 < eF)
                    ? (d2_packed(w1.x, qq, qpk2, qx, qy, qz) << 13) + w1.y
                    : 0xFFFFFFFFu;
                kk[3] = (jb + 3 >= sF && jb + 3 < eF)
                    ? (d2_packed(w1.z, qq, qpk2, qx, qy, qz) << 13) + w1.w
                    : 0xFFFFFFFFu;
#pragma unroll
                for (int u = 0; u < 4; ++u) {
                    c15 = min(c15, kk[u]);
                    sort2(c14, c15); sort2(c13, c14); sort2(c12, c13);
                    sort2(c11, c12); sort2(c10, c11); sort2(c9, c10);
                    sort2(c8, c9);   sort2(c7, c8);   sort2(c6, c7);
                    sort2(c5, c6);   sort2(c4, c5);   sort2(c3, c4);
                    sort2(c2, c3);   sort2(c1, c2);   sort2(c0, c1);
                }
            }
            for (int r = 0; r < 16; ++r) {
                unsigned m = c0;
                m = min(m, (unsigned)__shfl_xor((int)m, 1, 64));
                m = min(m, (unsigned)__shfl_xor((int)m, 2, 64));
                m = min(m, (unsigned)__shfl_xor((int)m, 4, 64));
                m = min(m, (unsigned)__shfl_xor((int)m, 8, 64));
                m = min(m, (unsigned)__shfl_xor((int)m, 16, 64));
                m = min(m, (unsigned)__shfl_xor((int)m, 32, 64));
                if (lane == r) sKnn[wv][r] = (int)(m & 8191u);
                bool win = (c0 == m);
                c0 = win ? c1 : c0;    c1 = win ? c2 : c1;
                c2 = win ? c3 : c2;    c3 = win ? c4 : c3;
                c4 = win ? c5 : c4;    c5 = win ? c6 : c5;
                c6 = win ? c7 : c6;    c7 = win ? c8 : c7;
                c8 = win ? c9 : c8;    c9 = win ? c10 : c9;
                c10 = win ? c11 : c10; c11 = win ? c12 : c11;
                c12 = win ? c13 : c12; c13 = win ? c14 : c13;
                c14 = win ? c15 : c14; c15 = win ? 0xFFFFFFFFu : c15;
            }
        }
    }

    // ---- pre-barrier gathers: jA/pc + xk ONLY (xvv deferred past GEMM2;
    //      sKnn[wv] is wave-local, needs no barrier) ----
    const int jA = sKnn[wv][col];
    const int4 jC = *(const int4*)&sKnn[wv][g * 4];
    const int jr[4] = {jC.x, jC.y, jC.z, jC.w};
    const int4 pc = idx4[jA];
    float xkv[4][4];
#pragma unroll
    for (int r = 0; r < 4; r++)
#pragma unroll
        for (int f = 0; f < 4; f++)
            xkv[r][f] = xk[jr[r] * 64 + f * 16 + col];

    __syncthreads();  // weights staged; gathers complete during the wait

    // ---- phase 2: attn ----
    _Float16* scr = sscr[wv];

    // ---- p_r (pr stays LIVE to the einsum) ----
    const float px = (float)(pc.y - qx);
    const float py = (float)(pc.z - qy);
    const float pz = (float)(pc.w - qz);
    f32x4 pr[4];
#if __has_builtin(__builtin_amdgcn_mfma_f32_16x16x16f16)
    {
        f16x4 aph;
#pragma unroll
        for (int j = 0; j < 4; j++) {
            int h = g * 4 + j;
            float v = px * sWp1[h] + py * sWp1[16 + h] + pz * sWp1[32 + h];
            v = fmaxf(v * sPg[h] + sPb[h], 0.f);
            aph[j] = (_Float16)v;
        }
#pragma unroll
        for (int f = 0; f < 4; f++) {
            f16x4 bP;
#pragma unroll
            for (int j = 0; j < 4; j++)
                bP[j] = (_Float16)Wp2[(g * 4 + j) * 64 + f * 16 + col];
            f32x4 cini;
#pragma unroll
            for (int r = 0; r < 4; r++) cini[r] = bp2c[f];
            pr[f] = __builtin_amdgcn_mfma_f32_16x16x16f16(aph, bP, cini,
                                                          0, 0, 0);
        }
    }
#else
    {
        f16x8 aph;
#pragma unroll
        for (int j = 0; j < 8; j++) {
            int h = g * 8 + j;
            float v = 0.f;
            if (g < 2) {
                v = px * sWp1[h] + py * sWp1[16 + h] + pz * sWp1[32 + h];
                v = fmaxf(v * sPg[h] + sPb[h], 0.f);
            }
            aph[j] = (_Float16)v;
        }
#pragma unroll
        for (int f = 0; f < 4; f++) {
            f16x8 bP;
#pragma unroll
            for (int j = 0; j < 8; j++) {
                int h = g * 8 + j;
                bP[j] = (g < 2) ? (_Float16)Wp2[h * 64 + f * 16 + col]
                                : (_Float16)0.f;
            }
            f32x4 cini;
#pragma unroll
            for (int r = 0; r < 4; r++) cini[r] = bp2c[f];
            pr[f] = __builtin_amdgcn_mfma_f32_16x16x32_f16(aph, bP, cini,
                                                           0, 0, 0);
        }
    }
#endif
    // ---- GEMM1, K-chunked through 16x40 scr (no vvr; xvv not loaded) ----
    f32x4 acc1[8];
#pragma unroll
    for (int f = 0; f < 8; f++)
#pragma unroll
        for (int r = 0; r < 4; r++) acc1[f][r] = 0.f;
#pragma unroll
    for (int kc = 0; kc < 2; kc++) {
#pragma unroll
        for (int fp = 0; fp < 2; fp++) {
            int f = kc * 2 + fp;
#pragma unroll
            for (int r = 0; r < 4; r++) {
                float w0 = xkv[r][f] - xqv[f] + pr[f][r];
                float uu = fmaxf(w0 * g1c[f] + b1c[f], 0.f);
                scr[(g * 4 + r) * 40 + fp * 16 + col] = (_Float16)uu;
            }
        }
        f16x8 au = *(const f16x8*)&scr[col * 40 + g * 8];
#pragma unroll
        for (int f = 0; f < 8; f++) {
            f16x8 bw = *(const f16x8*)
                &sW1t[(f * 16 + col) * 72 + kc * 32 + g * 8];
            acc1[f] = __builtin_amdgcn_mfma_f32_16x16x32_f16(au, bw, acc1[f],
                                                             0, 0, 0);
        }
    }
    // ---- o1 epilogue to f16 regs (frees acc1) ----
    _Float16 o1v[8][4];
#pragma unroll
    for (int f = 0; f < 8; f++) {
        float gn = sg2[f * 16 + col], bs = sb2[f * 16 + col];
#pragma unroll
        for (int r = 0; r < 4; r++)
            o1v[f][r] = (_Float16)fmaxf(acc1[f][r] * gn + bs, 0.f);
    }
    // ---- GEMM2, K-chunked (bw2 dropped: cancels in softmax over s) ----
    f32x4 accL[4];
#pragma unroll
    for (int f = 0; f < 4; f++)
#pragma unroll
        for (int r = 0; r < 4; r++) accL[f][r] = 0.f;
#pragma unroll
    for (int c = 0; c < 4; c++) {
#pragma unroll
        for (int fp = 0; fp < 2; fp++)
#pragma unroll
            for (int r = 0; r < 4; r++)
                scr[(g * 4 + r) * 40 + fp * 16 + col] = o1v[c * 2 + fp][r];
        f16x8 ao = *(const f16x8*)&scr[col * 40 + g * 8];
#pragma unroll
        for (int f = 0; f < 4; f++) {
            f16x8 bw = *(const f16x8*)
                &sW2t[(f * 16 + col) * 136 + c * 32 + g * 8];
            accL[f] = __builtin_amdgcn_mfma_f32_16x16x32_f16(ao, bw, accL[f],
                                                             0, 0, 0);
        }
    }
    // ---- DEFERRED xvv gather (acc1/o1v dead now; live set is small) ----
    float xvv[4][4];
#pragma unroll
    for (int r = 0; r < 4; r++)
#pragma unroll
        for (int f = 0; f < 4; f++)
            xvv[r][f] = xv[jr[r] * 64 + f * 16 + col];
    // ---- softmax over s + einsum (vvr folded: xvv + pr inline) ----
    float outv[4];
#pragma unroll
    for (int f = 0; f < 4; f++) {
        float mx = fmaxf(fmaxf(accL[f][0], accL[f][1]),
                         fmaxf(accL[f][2], accL[f][3]));
        mx = fmaxf(mx, __shfl_xor(mx, 16, 64));
        mx = fmaxf(mx, __shfl_xor(mx, 32, 64));
        float sum = 0.f, part = 0.f;
#pragma unroll
        for (int r = 0; r < 4; r++) {
            float e = __expf(accL[f][r] - mx);
            sum += e;
            part = fmaf(e, xvv[r][f] + pr[f][r], part);
        }
        sum += __shfl_xor(sum, 16, 64);
        sum += __shfl_xor(sum, 32, 64);
        part += __shfl_xor(part, 16, 64);
        part += __shfl_xor(part, 32, 64);
        outv[f] = part / sum;
    }
    float val = (g == 0) ? outv[0]
              : (g == 1) ? outv[1]
              : (g == 2) ? outv[2] : outv[3];
    attn[q * 64 + lane] = val;
}

// ---------------------------------------------------------------------------
// K3: FUSED MFMA-f16 head (verbatim — protected).
// ---------------------------------------------------------------------------
__global__ __launch_bounds__(256) void head_kernel(
    const float* __restrict__ feats, const float* __restrict__ attn,
    const _Float16* __restrict__ Wc1tG, const float* __restrict__ cg1,
    const float* __restrict__ cb1, const _Float16* __restrict__ Wc2tG,
    const float* __restrict__ cg2, const float* __restrict__ cb2,
    const _Float16* __restrict__ Wc3tG, const float* __restrict__ bc3,
    const float* __restrict__ lng, const float* __restrict__ lnb,
    float* __restrict__ out)
{
    __shared__ _Float16 sWt[128 * 136];
    __shared__ _Float16 sX[16 * 136];
    __shared__ _Float16 sY[16 * 136];
    __shared__ float sOut[16 * 68];
    __shared__ float sga[128], sba[128], sgb[128], sbb[128];
    __shared__ float sbc3[64], slng[64], slnb[64];

    const int t = threadIdx.x;
    const int lane = t & 63;
    const int wv = t >> 6;  // 0..3
    const int col = lane & 15, g = lane >> 4;
    const int row0 = blockIdx.x * 16;

    {
        int r = t >> 4, c0 = (t & 15) * 8;
        const float* src = (c0 < 64) ? (feats + (row0 + r) * 64 + c0)
                                     : (attn + (row0 + r) * 64 + (c0 - 64));
        float4 v0 = ((const float4*)src)[0];
        float4 v1 = ((const float4*)src)[1];
        _Float16* dst = &sX[r * 136 + c0];
        dst[0] = (_Float16)v0.x; dst[1] = (_Float16)v0.y;
        dst[2] = (_Float16)v0.z; dst[3] = (_Float16)v0.w;
        dst[4] = (_Float16)v1.x; dst[5] = (_Float16)v1.y;
        dst[6] = (_Float16)v1.z; dst[7] = (_Float16)v1.w;
    }
    auto stageWT = [&](const _Float16* WT, int chunks) {
        for (int i = t; i < chunks; i += 256) {
            int n = i >> 4, ko = i & 15;
            *(f16x8*)&sWt[n * 136 + ko * 8] =
                *(const f16x8*)&WT[n * 128 + ko * 8];
        }
    };
    stageWT(Wc1tG, 2048);
    if (t < 128) {
        sga[t] = cg1[t] * BN_INV; sba[t] = cb1[t];
        sgb[t] = cg2[t] * BN_INV; sbb[t] = cb2[t];
    } else if (t < 192) {
        int o = t - 128;
        sbc3[o] = bc3[o]; slng[o] = lng[o]; slnb[o] = lnb[o];
    }
    __syncthreads();
    // L1: 16x128 = 8 col-tiles; wave wv covers cols wv*32..wv*32+31
    {
        f16x8 ax[4];
#pragma unroll
        for (int kc = 0; kc < 4; kc++)
            ax[kc] = *(const f16x8*)&sX[col * 136 + kc * 32 + g * 8];
#pragma unroll
        for (int ft = 0; ft < 2; ft++) {
            int n = wv * 32 + ft * 16 + col;
            f32x4 acc;
#pragma unroll
            for (int r = 0; r < 4; r++) acc[r] = 0.f;
#pragma unroll
            for (int kc = 0; kc < 4; kc++) {
                f16x8 bw = *(const f16x8*)&sWt[n * 136 + kc * 32 + g * 8];
                acc = __builtin_amdgcn_mfma_f32_16x16x32_f16(ax[kc], bw, acc,
                                                             0, 0, 0);
            }
            float gn = sga[n], bs = sba[n];
#pragma unroll
            for (int r = 0; r < 4; r++)
                sY[(g * 4 + r) * 136 + n] =
                    (_Float16)fmaxf(acc[r] * gn + bs, 0.f);
        }
    }
    __syncthreads();
    stageWT(Wc2tG, 2048);
    __syncthreads();
    // L2: sY -> sX
    {
        f16x8 ax[4];
#pragma unroll
        for (int kc = 0; kc < 4; kc++)
            ax[kc] = *(const f16x8*)&sY[col * 136 + kc * 32 + g * 8];
#pragma unroll
        for (int ft = 0; ft < 2; ft++) {
            int n = wv * 32 + ft * 16 + col;
            f32x4 acc;
#pragma unroll
            for (int r = 0; r < 4; r++) acc[r] = 0.f;
#pragma unroll
            for (int kc = 0; kc < 4; kc++) {
                f16x8 bw = *(const f16x8*)&sWt[n * 136 + kc * 32 + g * 8];
                acc = __builtin_amdgcn_mfma_f32_16x16x32_f16(ax[kc], bw, acc,
                                                             0, 0, 0);
            }
            float gn = sgb[n], bs = sbb[n];
#pragma unroll
            for (int r = 0; r < 4; r++)
                sX[(g * 4 + r) * 136 + n] =
                    (_Float16)fmaxf(acc[r] * gn + bs, 0.f);
        }
    }
    __syncthreads();
    stageWT(Wc3tG, 1024);
    __syncthreads();
    // L3: 16x64; wave wv covers cols wv*16..wv*16+15
    {
        f16x8 ax[4];
#pragma unroll
        for (int kc = 0; kc < 4; kc++)
            ax[kc] = *(const f16x8*)&sX[col * 136 + kc * 32 + g * 8];
        int n = wv * 16 + col;
        f32x4 acc;
        float bias = sbc3[n];
#pragma unroll
        for (int r = 0; r < 4; r++) acc[r] = bias;
#pragma unroll
        for (int kc = 0; kc < 4; kc++) {
            f16x8 bw = *(const f16x8*)&sWt[n * 136 + kc * 32 + g * 8];
            acc = __builtin_amdgcn_mfma_f32_16x16x32_f16(ax[kc], bw, acc,
                                                         0, 0, 0);
        }
#pragma unroll
        for (int r = 0; r < 4; r++)
            sOut[(g * 4 + r) * 68 + n] = acc[r];
    }
    __syncthreads();
    // LN epilogue: r = t>>4, 16 lanes per row, width-16 shuffle
    {
        int r = t >> 4, o0 = (t & 15) * 4;
        float v[4];
        float s1 = 0.f, s2 = 0.f;
#pragma unroll
        for (int k = 0; k < 4; k++) {
            v[k] = sOut[r * 68 + o0 + k];
            s1 += v[k];
            s2 = fmaf(v[k], v[k], s2);
        }
#pragma unroll
        for (int d = 1; d < 16; d <<= 1) {
            s1 += __shfl_xor(s1, d, 16);
            s2 += __shfl_xor(s2, d, 16);
        }
        float m = s1 * (1.f / 64.f);
        float var = s2 * (1.f / 64.f) - m * m;
        float inv = 1.f / sqrtf(var + LN_EPS);
        float* dst = out + (row0 + r) * 64;
#pragma unroll
        for (int k = 0; k < 4; k++) {
            int o = o0 + k;
            dst[o] = (v[k] - m) * inv * slng[o] + slnb[o];
        }
    }
}

// ---------------------------------------------------------------------------
extern "C" void kernel_launch(void* const* d_in, const int* in_sizes, int n_in,
                              void* d_out, int out_size, void* d_ws,
                              size_t ws_size, hipStream_t stream)
{
    const int* indices = (const int*)d_in[0];
    const float* feats = (const float*)d_in[1];
    const float* Wq = (const float*)d_in[2];
    const float* bq = (const float*)d_in[3];
    const float* Wk = (const float*)d_in[4];
    const float* bk = (const float*)d_in[5];
    const float* Wv = (const float*)d_in[6];
    const float* bv = (const float*)d_in[7];
    const float* Wp1 = (const float*)d_in[8];
    const float* pg = (const float*)d_in[9];
    const float* pb = (const float*)d_in[10];
    const float* Wp2 = (const float*)d_in[11];
    const float* bp2 = (const float*)d_in[12];
    const float* wg1 = (const float*)d_in[13];
    const float* wb1 = (const float*)d_in[14];
    const float* Ww1 = (const float*)d_in[15];
    const float* wg2 = (const float*)d_in[16];
    const float* wb2 = (const float*)d_in[17];
    const float* Ww2 = (const float*)d_in[18];
    const float* Wc1 = (const float*)d_in[20];
    const float* cg1 = (const float*)d_in[21];
    const float* cb1 = (const float*)d_in[22];
    const float* Wc2 = (const float*)d_in[23];
    const float* cg2 = (const float*)d_in[24];
    const float* cb2 = (const float*)d_in[25];
    const float* Wc3 = (const float*)d_in[26];
    const float* bc3 = (const float*)d_in[27];
    const float* lng = (const float*)d_in[28];
    const float* lnb = (const float*)d_in[29];

    float* out = (float*)d_out;
    float* ws = (float*)d_ws;
    float* xq = ws;
    float* xk = xq + N * C;
    float* xv = xk + N * C;
    float* attn = xv + N * C;
    int* knn = (int*)(attn + N * C);   // unused now; layout kept
    _Float16* wt16 = (_Float16*)(knn + N * 16);
    _Float16* W1tG = wt16;              // 128 x 64
    _Float16* W2tG = W1tG + 8192;       // 64 x 128
    _Float16* Wc1tG = W2tG + 8192;      // 128 x 128
    _Float16* Wc2tG = Wc1tG + 16384;    // 128 x 128
    _Float16* Wc3tG = Wc2tG + 16384;    // 64 x 128
    // x-sorted point array (16B-aligned) + 768-entry slack for prefetch /
    // batched-fallback over-reads (values masked), then cdf[129].
    uint2* sortedG = (uint2*)(Wc3tG + 8192);
    int* cdfG = (int*)(sortedG + 8192 + 768);

    prep_kernel<<<70, 512, 32768, stream>>>(
        (const int4*)indices, feats, Wq, bq, Wk, bk, Wv, bv, xq, xk, xv,
        Ww1, Ww2, Wc1, Wc2, Wc3, W1tG, W2tG, Wc1tG, Wc2tG, Wc3tG,
        sortedG, cdfG);
    knnattn_kernel<<<1024, 512, 0, stream>>>(
        (const int4*)indices, sortedG, cdfG, xq, xk, xv, Wp1, pg, pb, Wp2,
        bp2, wg1, wb1, W1tG, wg2, wb2, W2tG, attn);
    head_kernel<<<512, 256, 0, stream>>>(feats, attn, Wc1tG, cg1, cb1, Wc2tG,
                                         cg2, cb2, Wc3tG, bc3, lng, lnb, out);
}